// Round 14
// baseline (137.421 us; speedup 1.0000x reference)
//
#include <hip/hip_runtime.h>
#include <hip/hip_bf16.h>

// Problem constants
#define B_ 128
#define S_ 512
#define C_ 64
#define H_ 4
#define D_ 32
// SCALE * log2(e): folded into Wq/bq at prep so softmax uses raw exp2
#define QSCALE_LOG2E 0.25505654249765306f

typedef __attribute__((ext_vector_type(8))) short bf16x8;
typedef __attribute__((ext_vector_type(8))) unsigned short u16x8;
typedef __attribute__((ext_vector_type(4))) float f32x4;
typedef __attribute__((ext_vector_type(4))) unsigned int u32x4;
typedef __attribute__((ext_vector_type(2))) unsigned int u32x2;

__device__ __forceinline__ unsigned short f2bf(float f) {
    unsigned int u = __float_as_uint(f);
    u = (u + 0x7FFFu + ((u >> 16) & 1u)) >> 16;   // RNE
    return (unsigned short)u;
}
// packed f32 pair -> bf16x2 in one u32 (low = a, high = b). Compiler
// intrinsic (no inline asm); memcpy pun (defined behavior, zero-cost).
__device__ __forceinline__ unsigned int pk2(float a, float b) {
    __hip_bfloat162 h = __float22bfloat162_rn(float2{a, b});
    unsigned int r;
    __builtin_memcpy(&r, &h, sizeof(r));
    return r;
}

// ---------------- K0: weight prep (1 block, round-6 proven) ----------------
// Wt[384][64] bf16: Wt[m*128 + h*32 + d][c] = W_m[h][c][d] (*scale for Q)
// bias_all[384] fp32 (scaled for Q)
__global__ __launch_bounds__(256) void wprep_kernel(
    const float* __restrict__ Wq, const float* __restrict__ bq,
    const float* __restrict__ Wk, const float* __restrict__ bk,
    const float* __restrict__ Wv, const float* __restrict__ bv,
    unsigned short* __restrict__ Wt, float* __restrict__ bias)
{
    const int tid = threadIdx.x;
    for (int idx = tid; idx < 3 * 8192; idx += 256) {
        int m = idx >> 13, f = idx & 8191;
        int h = f >> 11, c = (f >> 5) & 63, d = f & 31;
        const float* W = (m == 0) ? Wq : (m == 1) ? Wk : Wv;
        float v = W[f] * ((m == 0) ? QSCALE_LOG2E : 1.0f);
        Wt[(size_t)(m * 128 + h * 32 + d) * 64 + c] = f2bf(v);
    }
    for (int idx = tid; idx < 384; idx += 256) {
        int m = idx >> 7, o = idx & 127;
        const float* bs = (m == 0) ? bq : (m == 1) ? bk : bv;
        bias[idx] = bs[o] * ((m == 0) ? QSCALE_LOG2E : 1.0f);
    }
}

// ---------------- K1: MFMA QKV projection (round-6 proven) ----------------
__global__ __launch_bounds__(256, 4) void qkv_kernel(
    const float* __restrict__ X, const unsigned short* __restrict__ Wt,
    const float* __restrict__ bias,
    unsigned short* __restrict__ Qo, unsigned short* __restrict__ Ko,
    unsigned short* __restrict__ Vo)
{
    __shared__ unsigned int Xs[128 * 36];   // bf16 [128][72] (72 = 64 + 8 pad)

    const int m    = blockIdx.y;
    const int tid  = threadIdx.x;
    const int row0 = blockIdx.x * 128;
    const int w    = tid >> 6, lane = tid & 63;
    const int lq   = lane & 15, lg = lane >> 4;

    {
        const float4* Xg = reinterpret_cast<const float4*>(X + (size_t)row0 * C_);
        #pragma unroll
        for (int k = 0; k < 8; ++k) {
            int f4 = tid + k * 256;
            int r = f4 >> 4, c4 = f4 & 15;
            float4 x = Xg[f4];
            u32x2 p;
            p[0] = pk2(x.x, x.y);
            p[1] = pk2(x.z, x.w);
            *reinterpret_cast<u32x2*>(&Xs[r * 36 + c4 * 2]) = p;
        }
    }
    __syncthreads();

    const int b  = row0 / S_;
    const int sb = row0 % S_;
    const unsigned short* Wtm = Wt + (size_t)(m * 128) * 64;
    const float* bm = bias + m * 128;
    unsigned short* Out = (m == 0) ? Qo : (m == 1) ? Ko : Vo;

    #pragma unroll
    for (int ni = 0; ni < 2; ++ni) {
        const int nt = 2 * w + ni;           // n-tile 0..7
        const int n0 = nt * 16;
        bf16x8 wf0 = *reinterpret_cast<const bf16x8*>(Wtm + (size_t)(n0 + lq) * 64 + lg * 8);
        bf16x8 wf1 = *reinterpret_cast<const bf16x8*>(Wtm + (size_t)(n0 + lq) * 64 + 32 + lg * 8);

        if (m != 2) {
            const int nrow = n0 + 4 * lg;                 // 4 consecutive n
            const int h = nrow >> 5, d0 = nrow & 31;
            f32x4 bv4 = *reinterpret_cast<const f32x4*>(bm + nrow);
            unsigned short* obase = Out + ((size_t)(b * H_ + h) * S_ + sb) * D_ + d0;
            #pragma unroll
            for (int st = 0; st < 8; ++st) {
                const unsigned int* xr = &Xs[(st * 16 + lq) * 36];
                bf16x8 xf0 = *reinterpret_cast<const bf16x8*>(xr + lg * 4);
                bf16x8 xf1 = *reinterpret_cast<const bf16x8*>(xr + 16 + lg * 4);
                f32x4 acc;
                acc[0] = 0.f; acc[1] = 0.f; acc[2] = 0.f; acc[3] = 0.f;
                acc = __builtin_amdgcn_mfma_f32_16x16x32_bf16(wf0, xf0, acc, 0, 0, 0);
                acc = __builtin_amdgcn_mfma_f32_16x16x32_bf16(wf1, xf1, acc, 0, 0, 0);
                u32x2 cc;
                cc[0] = pk2(acc[0] + bv4[0], acc[1] + bv4[1]);
                cc[1] = pk2(acc[2] + bv4[2], acc[3] + bv4[3]);
                *reinterpret_cast<u32x2*>(obase + (size_t)(st * 16 + lq) * D_) = cc;
            }
        } else {
            const int ncol = n0 + lq;                     // one n (= h,d) per lane
            const int h = ncol >> 5, d = ncol & 31;
            const float bsc = bm[ncol];
            unsigned short* obase = Out + ((size_t)(b * H_ + h) * S_) * D_
                                  + (size_t)d * S_ + sb + 4 * lg;
            #pragma unroll
            for (int st = 0; st < 8; ++st) {
                const unsigned int* xr = &Xs[(st * 16 + lq) * 36];
                bf16x8 xf0 = *reinterpret_cast<const bf16x8*>(xr + lg * 4);
                bf16x8 xf1 = *reinterpret_cast<const bf16x8*>(xr + 16 + lg * 4);
                f32x4 acc;
                acc[0] = 0.f; acc[1] = 0.f; acc[2] = 0.f; acc[3] = 0.f;
                acc = __builtin_amdgcn_mfma_f32_16x16x32_bf16(xf0, wf0, acc, 0, 0, 0);
                acc = __builtin_amdgcn_mfma_f32_16x16x32_bf16(xf1, wf1, acc, 0, 0, 0);
                u32x2 cc;
                cc[0] = pk2(acc[0] + bsc, acc[1] + bsc);
                cc[1] = pk2(acc[2] + bsc, acc[3] + bsc);
                *reinterpret_cast<u32x2*>(obase + st * 16) = cc;
            }
        }
    }
}

// ---------------- K2: MFMA attention (asm-free guts, qi=2 TLP geometry) ----
// grid 2048 (bh*4+quarter), 256 thr = 4 waves; wave owns 32 q rows (qi=2).
// 8192 waves total -> up to 32 waves/CU: TLP hides L2 latency.
// NOTE: qi=2 failed only in builds containing a TBAA stack pun (R3) or
// inline-asm cvtpk (R8/R9); this build has neither (R4 precedent passes).
// K-dim slot permutation: slot (lg,e) -> t = 4*lg+e (e<4), 16+4*lg+(e-4) (e>=4).
__global__ __launch_bounds__(256, 4) void attn_kernel(
    const unsigned short* __restrict__ Qb, const unsigned short* __restrict__ Kb,
    const unsigned short* __restrict__ Vtb, unsigned short* __restrict__ ctx)
{
    const int bid  = blockIdx.x;
    const int bh   = bid >> 2, quarter = bid & 3;
    const int b    = bh >> 2, h = bh & 3;
    const int tid  = threadIdx.x;
    const int w    = tid >> 6, lane = tid & 63;
    const int lq   = lane & 15, lg = lane >> 4;

    const unsigned short* Qp = Qb  + (size_t)bh * (S_ * D_);
    const unsigned short* Kp = Kb  + (size_t)bh * (S_ * D_);
    const unsigned short* Vp = Vtb + (size_t)bh * (S_ * D_);

    const int q0 = quarter * 128 + w * 32;

    bf16x8 qf[2];
    #pragma unroll
    for (int qi = 0; qi < 2; ++qi)
        qf[qi] = *reinterpret_cast<const bf16x8*>(
            Qp + (size_t)(q0 + qi * 16 + lq) * D_ + lg * 8);

    f32x4 acc[2][2];
    float lsum[2];
    #pragma unroll
    for (int qi = 0; qi < 2; ++qi) {
        lsum[qi] = 0.f;
        #pragma unroll
        for (int dt = 0; dt < 2; ++dt) {
            acc[qi][dt][0] = 0.f; acc[qi][dt][1] = 0.f;
            acc[qi][dt][2] = 0.f; acc[qi][dt][3] = 0.f;
        }
    }

    const unsigned short* vp0 = Vp + (size_t)lq * S_ + 4 * lg;         // d=lq
    const unsigned short* vp1 = Vp + (size_t)(16 + lq) * S_ + 4 * lg;  // d=16+lq

    for (int tc = 0; tc < 16; ++tc) {
        const int t0 = tc * 32;
        bf16x8 k0 = *reinterpret_cast<const bf16x8*>(Kp + (size_t)(t0 + lq) * D_ + lg * 8);
        bf16x8 k1 = *reinterpret_cast<const bf16x8*>(Kp + (size_t)(t0 + 16 + lq) * D_ + lg * 8);

        u32x2 va = *reinterpret_cast<const u32x2*>(vp0 + t0);
        u32x2 vb = *reinterpret_cast<const u32x2*>(vp0 + t0 + 16);
        u32x2 vc = *reinterpret_cast<const u32x2*>(vp1 + t0);
        u32x2 vd = *reinterpret_cast<const u32x2*>(vp1 + t0 + 16);
        u32x4 v0u; v0u[0] = va[0]; v0u[1] = va[1]; v0u[2] = vb[0]; v0u[3] = vb[1];
        u32x4 v1u; v1u[0] = vc[0]; v1u[1] = vc[1]; v1u[2] = vd[0]; v1u[3] = vd[1];
        bf16x8 v0 = __builtin_bit_cast(bf16x8, v0u);
        bf16x8 v1 = __builtin_bit_cast(bf16x8, v1u);

        #pragma unroll
        for (int qi = 0; qi < 2; ++qi) {
            f32x4 z; z[0] = 0.f; z[1] = 0.f; z[2] = 0.f; z[3] = 0.f;
            f32x4 s0 = __builtin_amdgcn_mfma_f32_16x16x32_bf16(k0, qf[qi], z, 0, 0, 0);
            f32x4 s1 = __builtin_amdgcn_mfma_f32_16x16x32_bf16(k1, qf[qi], z, 0, 0, 0);
            float pa = __builtin_amdgcn_exp2f(s0[0]);
            float pb = __builtin_amdgcn_exp2f(s0[1]);
            float pc = __builtin_amdgcn_exp2f(s0[2]);
            float pd = __builtin_amdgcn_exp2f(s0[3]);
            float pe = __builtin_amdgcn_exp2f(s1[0]);
            float pf = __builtin_amdgcn_exp2f(s1[1]);
            float pg = __builtin_amdgcn_exp2f(s1[2]);
            float ph = __builtin_amdgcn_exp2f(s1[3]);
            lsum[qi] += ((pa + pb) + (pc + pd)) + ((pe + pf) + (pg + ph));
            u32x4 pu;
            pu[0] = pk2(pa, pb);
            pu[1] = pk2(pc, pd);
            pu[2] = pk2(pe, pf);
            pu[3] = pk2(pg, ph);
            bf16x8 pfr = __builtin_bit_cast(bf16x8, pu);
            acc[qi][0] = __builtin_amdgcn_mfma_f32_16x16x32_bf16(v0, pfr, acc[qi][0], 0, 0, 0);
            acc[qi][1] = __builtin_amdgcn_mfma_f32_16x16x32_bf16(v1, pfr, acc[qi][1], 0, 0, 0);
        }
    }

    #pragma unroll
    for (int qi = 0; qi < 2; ++qi) {
        float lt = lsum[qi];
        lt += __shfl_xor(lt, 16, 64);
        lt += __shfl_xor(lt, 32, 64);
        const float inv = 1.0f / lt;
        const int qg = q0 + qi * 16 + lq;
        #pragma unroll
        for (int dt = 0; dt < 2; ++dt) {
            u32x2 c;
            c[0] = pk2(acc[qi][dt][0] * inv, acc[qi][dt][1] * inv);
            c[1] = pk2(acc[qi][dt][2] * inv, acc[qi][dt][3] * inv);
            unsigned short* cp = ctx + ((size_t)(b * S_ + qg)) * (H_ * D_)
                               + h * D_ + dt * 16 + lg * 4;
            *reinterpret_cast<u32x2*>(cp) = c;
        }
    }
}

// ---------------- K3: output projection (bf16 ctx -> fp32 out) ----------------
__global__ __launch_bounds__(256) void out_kernel(
    const unsigned short* __restrict__ ctx, const float* __restrict__ Wo,
    const float* __restrict__ bo, float* __restrict__ out)
{
    __shared__ float4 Wos[128][8];
    const int tid = threadIdx.x;
    #pragma unroll
    for (int k = 0; k < 4; ++k) {
        int f4 = tid + k * 256;
        reinterpret_cast<float4*>(&Wos[0][0])[f4] =
            reinterpret_cast<const float4*>(Wo)[f4];
    }
    __syncthreads();

    const int r  = blockIdx.x * 32 + (tid >> 3);
    const int cq = tid & 7;
    const u32x4* c4 = reinterpret_cast<const u32x4*>(ctx + (size_t)r * 128);
    float4 b4 = reinterpret_cast<const float4*>(bo)[cq];
    float ax = b4.x, ay = b4.y, az = b4.z, aw = b4.w;

    #pragma unroll 4
    for (int o8 = 0; o8 < 16; ++o8) {
        u32x4 u = c4[o8];
        #pragma unroll
        for (int q = 0; q < 4; ++q) {
            float xlo = __uint_as_float(u[q] << 16);
            float xhi = __uint_as_float(u[q] & 0xFFFF0000u);
            float4 wlo = Wos[o8 * 8 + q * 2][cq];
            float4 whi = Wos[o8 * 8 + q * 2 + 1][cq];
            ax += xlo * wlo.x + xhi * whi.x;
            ay += xlo * wlo.y + xhi * whi.y;
            az += xlo * wlo.z + xhi * whi.z;
            aw += xlo * wlo.w + xhi * whi.w;
        }
    }
    reinterpret_cast<float4*>(out + (size_t)r * 32)[cq] = make_float4(ax, ay, az, aw);
}

extern "C" void kernel_launch(void* const* d_in, const int* in_sizes, int n_in,
                              void* d_out, int out_size, void* d_ws, size_t ws_size,
                              hipStream_t stream) {
    const float* X  = (const float*)d_in[0];
    const float* Wq = (const float*)d_in[1];
    const float* bq = (const float*)d_in[2];
    const float* Wk = (const float*)d_in[3];
    const float* bk = (const float*)d_in[4];
    const float* Wv = (const float*)d_in[5];
    const float* bv = (const float*)d_in[6];
    const float* Wo = (const float*)d_in[7];
    const float* bo = (const float*)d_in[8];
    float* out = (float*)d_out;

    const size_t per = (size_t)B_ * H_ * S_ * D_;            // 8388608
    const size_t need = 4 * per * sizeof(unsigned short) + 24576 * 2 + 384 * 4;
    if (ws_size < need) return;

    unsigned short* Qb   = (unsigned short*)d_ws;
    unsigned short* Kb   = Qb + per;
    unsigned short* Vtb  = Kb + per;
    unsigned short* ctx  = Vtb + per;
    unsigned short* Wt   = ctx + per;
    float*          bias = (float*)(Wt + 24576);

    wprep_kernel<<<1, 256, 0, stream>>>(Wq, bq, Wk, bk, Wv, bv, Wt, bias);
    qkv_kernel<<<dim3(512, 3), 256, 0, stream>>>(X, Wt, bias, Qb, Kb, Vtb);
    attn_kernel<<<2048, 256, 0, stream>>>(Qb, Kb, Vtb, ctx);
    out_kernel<<<2048, 256, 0, stream>>>(ctx, Wo, bo, out);
}

// Round 15
// 85.178 us; speedup vs baseline: 1.6133x; 1.6133x over previous
//
#include <hip/hip_runtime.h>
#include <hip/hip_bf16.h>

// Problem constants
#define B_ 128
#define S_ 512
#define C_ 64
#define H_ 4
#define D_ 32
// SCALE * log2(e): folded into Wq/bq at prep so softmax uses raw exp2
#define QSCALE_LOG2E 0.25505654249765306f

typedef __attribute__((ext_vector_type(8))) short bf16x8;
typedef __attribute__((ext_vector_type(8))) unsigned short u16x8;
typedef __attribute__((ext_vector_type(4))) float f32x4;
typedef __attribute__((ext_vector_type(4))) unsigned int u32x4;
typedef __attribute__((ext_vector_type(2))) unsigned int u32x2;

__device__ __forceinline__ unsigned short f2bf(float f) {
    unsigned int u = __float_as_uint(f);
    u = (u + 0x7FFFu + ((u >> 16) & 1u)) >> 16;   // RNE
    return (unsigned short)u;
}
// packed f32 pair -> bf16x2 in one u32 (low = a, high = b). Compiler
// intrinsic (no inline asm); memcpy pun (defined behavior, zero-cost).
__device__ __forceinline__ unsigned int pk2(float a, float b) {
    __hip_bfloat162 h = __float22bfloat162_rn(float2{a, b});
    unsigned int r;
    __builtin_memcpy(&r, &h, sizeof(r));
    return r;
}

// ---------------- K0: weight prep (97 blocks, parallel) ----------------
// Wt[384][64] bf16: Wt[m*128 + h*32 + d][c] = W_m[h][c][d] (*scale for Q)
// bias_all[384] fp32 (scaled for Q). bid<96: idx = bid*256+tid covers
// [0,24576) one element/thread (identical map to the grid-stride version).
__global__ __launch_bounds__(256) void wprep_kernel(
    const float* __restrict__ Wq, const float* __restrict__ bq,
    const float* __restrict__ Wk, const float* __restrict__ bk,
    const float* __restrict__ Wv, const float* __restrict__ bv,
    unsigned short* __restrict__ Wt, float* __restrict__ bias)
{
    const int bid = blockIdx.x, tid = threadIdx.x;
    if (bid < 96) {
        const int idx = bid * 256 + tid;         // 0..24575
        const int m = idx >> 13, f = idx & 8191;
        const int h = f >> 11, c = (f >> 5) & 63, d = f & 31;
        const float* W = (m == 0) ? Wq : (m == 1) ? Wk : Wv;
        float v = W[f] * ((m == 0) ? QSCALE_LOG2E : 1.0f);
        Wt[(size_t)(m * 128 + h * 32 + d) * 64 + c] = f2bf(v);
    } else {
        for (int idx = tid; idx < 384; idx += 256) {
            int m = idx >> 7, o = idx & 127;
            const float* bs = (m == 0) ? bq : (m == 1) ? bk : bv;
            bias[idx] = bs[o] * ((m == 0) ? QSCALE_LOG2E : 1.0f);
        }
    }
}

// ---------------- K1: MFMA QKV projection (round-6 proven) ----------------
__global__ __launch_bounds__(256, 4) void qkv_kernel(
    const float* __restrict__ X, const unsigned short* __restrict__ Wt,
    const float* __restrict__ bias,
    unsigned short* __restrict__ Qo, unsigned short* __restrict__ Ko,
    unsigned short* __restrict__ Vo)
{
    __shared__ unsigned int Xs[128 * 36];   // bf16 [128][72] (72 = 64 + 8 pad)

    const int m    = blockIdx.y;
    const int tid  = threadIdx.x;
    const int row0 = blockIdx.x * 128;
    const int w    = tid >> 6, lane = tid & 63;
    const int lq   = lane & 15, lg = lane >> 4;

    {
        const float4* Xg = reinterpret_cast<const float4*>(X + (size_t)row0 * C_);
        #pragma unroll
        for (int k = 0; k < 8; ++k) {
            int f4 = tid + k * 256;
            int r = f4 >> 4, c4 = f4 & 15;
            float4 x = Xg[f4];
            u32x2 p;
            p[0] = pk2(x.x, x.y);
            p[1] = pk2(x.z, x.w);
            *reinterpret_cast<u32x2*>(&Xs[r * 36 + c4 * 2]) = p;
        }
    }
    __syncthreads();

    const int b  = row0 / S_;
    const int sb = row0 % S_;
    const unsigned short* Wtm = Wt + (size_t)(m * 128) * 64;
    const float* bm = bias + m * 128;
    unsigned short* Out = (m == 0) ? Qo : (m == 1) ? Ko : Vo;

    #pragma unroll
    for (int ni = 0; ni < 2; ++ni) {
        const int nt = 2 * w + ni;           // n-tile 0..7
        const int n0 = nt * 16;
        bf16x8 wf0 = *reinterpret_cast<const bf16x8*>(Wtm + (size_t)(n0 + lq) * 64 + lg * 8);
        bf16x8 wf1 = *reinterpret_cast<const bf16x8*>(Wtm + (size_t)(n0 + lq) * 64 + 32 + lg * 8);

        if (m != 2) {
            const int nrow = n0 + 4 * lg;                 // 4 consecutive n
            const int h = nrow >> 5, d0 = nrow & 31;
            f32x4 bv4 = *reinterpret_cast<const f32x4*>(bm + nrow);
            unsigned short* obase = Out + ((size_t)(b * H_ + h) * S_ + sb) * D_ + d0;
            #pragma unroll
            for (int st = 0; st < 8; ++st) {
                const unsigned int* xr = &Xs[(st * 16 + lq) * 36];
                bf16x8 xf0 = *reinterpret_cast<const bf16x8*>(xr + lg * 4);
                bf16x8 xf1 = *reinterpret_cast<const bf16x8*>(xr + 16 + lg * 4);
                f32x4 acc;
                acc[0] = 0.f; acc[1] = 0.f; acc[2] = 0.f; acc[3] = 0.f;
                acc = __builtin_amdgcn_mfma_f32_16x16x32_bf16(wf0, xf0, acc, 0, 0, 0);
                acc = __builtin_amdgcn_mfma_f32_16x16x32_bf16(wf1, xf1, acc, 0, 0, 0);
                u32x2 cc;
                cc[0] = pk2(acc[0] + bv4[0], acc[1] + bv4[1]);
                cc[1] = pk2(acc[2] + bv4[2], acc[3] + bv4[3]);
                *reinterpret_cast<u32x2*>(obase + (size_t)(st * 16 + lq) * D_) = cc;
            }
        } else {
            const int ncol = n0 + lq;                     // one n (= h,d) per lane
            const int h = ncol >> 5, d = ncol & 31;
            const float bsc = bm[ncol];
            unsigned short* obase = Out + ((size_t)(b * H_ + h) * S_) * D_
                                  + (size_t)d * S_ + sb + 4 * lg;
            #pragma unroll
            for (int st = 0; st < 8; ++st) {
                const unsigned int* xr = &Xs[(st * 16 + lq) * 36];
                bf16x8 xf0 = *reinterpret_cast<const bf16x8*>(xr + lg * 4);
                bf16x8 xf1 = *reinterpret_cast<const bf16x8*>(xr + 16 + lg * 4);
                f32x4 acc;
                acc[0] = 0.f; acc[1] = 0.f; acc[2] = 0.f; acc[3] = 0.f;
                acc = __builtin_amdgcn_mfma_f32_16x16x32_bf16(xf0, wf0, acc, 0, 0, 0);
                acc = __builtin_amdgcn_mfma_f32_16x16x32_bf16(xf1, wf1, acc, 0, 0, 0);
                u32x2 cc;
                cc[0] = pk2(acc[0] + bsc, acc[1] + bsc);
                cc[1] = pk2(acc[2] + bsc, acc[3] + bsc);
                *reinterpret_cast<u32x2*>(obase + st * 16) = cc;
            }
        }
    }
}

// ---------------- K2: MFMA attention (round-12 frozen form) ----------
// grid 1024 (bh*2+half), 256 thr = 4 waves; wave owns 64 q rows (qi=4).
// Axis map: qi=2 = 82 us (R14), qi=4 = 49.7 us (R12), full unroll = 63 us
// spill (R13). This is the optimum of the explored space; keep rolled.
// K-dim slot permutation: slot (lg,e) -> t = 4*lg+e (e<4), 16+4*lg+(e-4) (e>=4).
__global__ __launch_bounds__(256, 4) void attn_kernel(
    const unsigned short* __restrict__ Qb, const unsigned short* __restrict__ Kb,
    const unsigned short* __restrict__ Vtb, unsigned short* __restrict__ ctx)
{
    const int bid  = blockIdx.x;
    const int bh   = bid >> 1, half = bid & 1;
    const int b    = bh >> 2, h = bh & 3;
    const int tid  = threadIdx.x;
    const int w    = tid >> 6, lane = tid & 63;
    const int lq   = lane & 15, lg = lane >> 4;

    const unsigned short* Qp = Qb  + (size_t)bh * (S_ * D_);
    const unsigned short* Kp = Kb  + (size_t)bh * (S_ * D_);
    const unsigned short* Vp = Vtb + (size_t)bh * (S_ * D_);

    const int q0 = half * 256 + w * 64;

    bf16x8 qf[4];
    #pragma unroll
    for (int qi = 0; qi < 4; ++qi)
        qf[qi] = *reinterpret_cast<const bf16x8*>(
            Qp + (size_t)(q0 + qi * 16 + lq) * D_ + lg * 8);

    f32x4 acc[4][2];
    float lsum[4];
    #pragma unroll
    for (int qi = 0; qi < 4; ++qi) {
        lsum[qi] = 0.f;
        #pragma unroll
        for (int dt = 0; dt < 2; ++dt) {
            acc[qi][dt][0] = 0.f; acc[qi][dt][1] = 0.f;
            acc[qi][dt][2] = 0.f; acc[qi][dt][3] = 0.f;
        }
    }

    const unsigned short* vp0 = Vp + (size_t)lq * S_ + 4 * lg;         // d=lq
    const unsigned short* vp1 = Vp + (size_t)(16 + lq) * S_ + 4 * lg;  // d=16+lq

    for (int tc = 0; tc < 16; ++tc) {
        const int t0 = tc * 32;
        bf16x8 k0 = *reinterpret_cast<const bf16x8*>(Kp + (size_t)(t0 + lq) * D_ + lg * 8);
        bf16x8 k1 = *reinterpret_cast<const bf16x8*>(Kp + (size_t)(t0 + 16 + lq) * D_ + lg * 8);

        u32x2 va = *reinterpret_cast<const u32x2*>(vp0 + t0);
        u32x2 vb = *reinterpret_cast<const u32x2*>(vp0 + t0 + 16);
        u32x2 vc = *reinterpret_cast<const u32x2*>(vp1 + t0);
        u32x2 vd = *reinterpret_cast<const u32x2*>(vp1 + t0 + 16);
        u32x4 v0u; v0u[0] = va[0]; v0u[1] = va[1]; v0u[2] = vb[0]; v0u[3] = vb[1];
        u32x4 v1u; v1u[0] = vc[0]; v1u[1] = vc[1]; v1u[2] = vd[0]; v1u[3] = vd[1];
        bf16x8 v0 = __builtin_bit_cast(bf16x8, v0u);
        bf16x8 v1 = __builtin_bit_cast(bf16x8, v1u);

        #pragma unroll
        for (int qi = 0; qi < 4; ++qi) {
            f32x4 z; z[0] = 0.f; z[1] = 0.f; z[2] = 0.f; z[3] = 0.f;
            f32x4 s0 = __builtin_amdgcn_mfma_f32_16x16x32_bf16(k0, qf[qi], z, 0, 0, 0);
            f32x4 s1 = __builtin_amdgcn_mfma_f32_16x16x32_bf16(k1, qf[qi], z, 0, 0, 0);
            float pa = __builtin_amdgcn_exp2f(s0[0]);
            float pb = __builtin_amdgcn_exp2f(s0[1]);
            float pc = __builtin_amdgcn_exp2f(s0[2]);
            float pd = __builtin_amdgcn_exp2f(s0[3]);
            float pe = __builtin_amdgcn_exp2f(s1[0]);
            float pf = __builtin_amdgcn_exp2f(s1[1]);
            float pg = __builtin_amdgcn_exp2f(s1[2]);
            float ph = __builtin_amdgcn_exp2f(s1[3]);
            lsum[qi] += ((pa + pb) + (pc + pd)) + ((pe + pf) + (pg + ph));
            u32x4 pu;
            pu[0] = pk2(pa, pb);
            pu[1] = pk2(pc, pd);
            pu[2] = pk2(pe, pf);
            pu[3] = pk2(pg, ph);
            bf16x8 pfr = __builtin_bit_cast(bf16x8, pu);
            acc[qi][0] = __builtin_amdgcn_mfma_f32_16x16x32_bf16(v0, pfr, acc[qi][0], 0, 0, 0);
            acc[qi][1] = __builtin_amdgcn_mfma_f32_16x16x32_bf16(v1, pfr, acc[qi][1], 0, 0, 0);
        }
    }

    #pragma unroll
    for (int qi = 0; qi < 4; ++qi) {
        float lt = lsum[qi];
        lt += __shfl_xor(lt, 16, 64);
        lt += __shfl_xor(lt, 32, 64);
        const float inv = 1.0f / lt;
        const int qg = q0 + qi * 16 + lq;
        #pragma unroll
        for (int dt = 0; dt < 2; ++dt) {
            u32x2 c;
            c[0] = pk2(acc[qi][dt][0] * inv, acc[qi][dt][1] * inv);
            c[1] = pk2(acc[qi][dt][2] * inv, acc[qi][dt][3] * inv);
            unsigned short* cp = ctx + ((size_t)(b * S_ + qg)) * (H_ * D_)
                               + h * D_ + dt * 16 + lg * 4;
            *reinterpret_cast<u32x2*>(cp) = c;
        }
    }
}

// ---------------- K3: output projection (bf16 ctx -> fp32 out) ----------------
__global__ __launch_bounds__(256) void out_kernel(
    const unsigned short* __restrict__ ctx, const float* __restrict__ Wo,
    const float* __restrict__ bo, float* __restrict__ out)
{
    __shared__ float4 Wos[128][8];
    const int tid = threadIdx.x;
    #pragma unroll
    for (int k = 0; k < 4; ++k) {
        int f4 = tid + k * 256;
        reinterpret_cast<float4*>(&Wos[0][0])[f4] =
            reinterpret_cast<const float4*>(Wo)[f4];
    }
    __syncthreads();

    const int r  = blockIdx.x * 32 + (tid >> 3);
    const int cq = tid & 7;
    const u32x4* c4 = reinterpret_cast<const u32x4*>(ctx + (size_t)r * 128);
    float4 b4 = reinterpret_cast<const float4*>(bo)[cq];
    float ax = b4.x, ay = b4.y, az = b4.z, aw = b4.w;

    #pragma unroll 4
    for (int o8 = 0; o8 < 16; ++o8) {
        u32x4 u = c4[o8];
        #pragma unroll
        for (int q = 0; q < 4; ++q) {
            float xlo = __uint_as_float(u[q] << 16);
            float xhi = __uint_as_float(u[q] & 0xFFFF0000u);
            float4 wlo = Wos[o8 * 8 + q * 2][cq];
            float4 whi = Wos[o8 * 8 + q * 2 + 1][cq];
            ax += xlo * wlo.x + xhi * whi.x;
            ay += xlo * wlo.y + xhi * whi.y;
            az += xlo * wlo.z + xhi * whi.z;
            aw += xlo * wlo.w + xhi * whi.w;
        }
    }
    reinterpret_cast<float4*>(out + (size_t)r * 32)[cq] = make_float4(ax, ay, az, aw);
}

extern "C" void kernel_launch(void* const* d_in, const int* in_sizes, int n_in,
                              void* d_out, int out_size, void* d_ws, size_t ws_size,
                              hipStream_t stream) {
    const float* X  = (const float*)d_in[0];
    const float* Wq = (const float*)d_in[1];
    const float* bq = (const float*)d_in[2];
    const float* Wk = (const float*)d_in[3];
    const float* bk = (const float*)d_in[4];
    const float* Wv = (const float*)d_in[5];
    const float* bv = (const float*)d_in[6];
    const float* Wo = (const float*)d_in[7];
    const float* bo = (const float*)d_in[8];
    float* out = (float*)d_out;

    const size_t per = (size_t)B_ * H_ * S_ * D_;            // 8388608
    const size_t need = 4 * per * sizeof(unsigned short) + 24576 * 2 + 384 * 4;
    if (ws_size < need) return;

    unsigned short* Qb   = (unsigned short*)d_ws;
    unsigned short* Kb   = Qb + per;
    unsigned short* Vtb  = Kb + per;
    unsigned short* ctx  = Vtb + per;
    unsigned short* Wt   = ctx + per;
    float*          bias = (float*)(Wt + 24576);

    wprep_kernel<<<97, 256, 0, stream>>>(Wq, bq, Wk, bk, Wv, bv, Wt, bias);
    qkv_kernel<<<dim3(512, 3), 256, 0, stream>>>(X, Wt, bias, Qb, Kb, Vtb);
    attn_kernel<<<1024, 256, 0, stream>>>(Qb, Kb, Vtb, ctx);
    out_kernel<<<2048, 256, 0, stream>>>(ctx, Wo, bo, out);
}

// Round 16
// 84.330 us; speedup vs baseline: 1.6296x; 1.0100x over previous
//
#include <hip/hip_runtime.h>
#include <hip/hip_bf16.h>

// Problem constants
#define B_ 128
#define S_ 512
#define C_ 64
#define H_ 4
#define D_ 32
// SCALE * log2(e): folded into Wq/bq at prep so softmax uses raw exp2
#define QSCALE_LOG2E 0.25505654249765306f

typedef __attribute__((ext_vector_type(8))) short bf16x8;
typedef __attribute__((ext_vector_type(8))) unsigned short u16x8;
typedef __attribute__((ext_vector_type(4))) float f32x4;
typedef __attribute__((ext_vector_type(4))) unsigned int u32x4;
typedef __attribute__((ext_vector_type(2))) unsigned int u32x2;

__device__ __forceinline__ unsigned short f2bf(float f) {
    unsigned int u = __float_as_uint(f);
    u = (u + 0x7FFFu + ((u >> 16) & 1u)) >> 16;   // RNE
    return (unsigned short)u;
}
// packed f32 pair -> bf16x2 in one u32 (low = a, high = b). Compiler
// intrinsic (no inline asm); memcpy pun (defined behavior, zero-cost).
__device__ __forceinline__ unsigned int pk2(float a, float b) {
    __hip_bfloat162 h = __float22bfloat162_rn(float2{a, b});
    unsigned int r;
    __builtin_memcpy(&r, &h, sizeof(r));
    return r;
}

// ---------------- K0: weight prep (97 blocks, round-15 proven) -------------
__global__ __launch_bounds__(256) void wprep_kernel(
    const float* __restrict__ Wq, const float* __restrict__ bq,
    const float* __restrict__ Wk, const float* __restrict__ bk,
    const float* __restrict__ Wv, const float* __restrict__ bv,
    unsigned short* __restrict__ Wt, float* __restrict__ bias)
{
    const int bid = blockIdx.x, tid = threadIdx.x;
    if (bid < 96) {
        const int idx = bid * 256 + tid;         // 0..24575
        const int m = idx >> 13, f = idx & 8191;
        const int h = f >> 11, c = (f >> 5) & 63, d = f & 31;
        const float* W = (m == 0) ? Wq : (m == 1) ? Wk : Wv;
        float v = W[f] * ((m == 0) ? QSCALE_LOG2E : 1.0f);
        Wt[(size_t)(m * 128 + h * 32 + d) * 64 + c] = f2bf(v);
    } else {
        for (int idx = tid; idx < 384; idx += 256) {
            int m = idx >> 7, o = idx & 127;
            const float* bs = (m == 0) ? bq : (m == 1) ? bk : bv;
            bias[idx] = bs[o] * ((m == 0) ? QSCALE_LOG2E : 1.0f);
        }
    }
}

// ---------------- K1: MFMA QKV projection (round-6 proven) ----------------
__global__ __launch_bounds__(256, 4) void qkv_kernel(
    const float* __restrict__ X, const unsigned short* __restrict__ Wt,
    const float* __restrict__ bias,
    unsigned short* __restrict__ Qo, unsigned short* __restrict__ Ko,
    unsigned short* __restrict__ Vo)
{
    __shared__ unsigned int Xs[128 * 36];   // bf16 [128][72] (72 = 64 + 8 pad)

    const int m    = blockIdx.y;
    const int tid  = threadIdx.x;
    const int row0 = blockIdx.x * 128;
    const int w    = tid >> 6, lane = tid & 63;
    const int lq   = lane & 15, lg = lane >> 4;

    {
        const float4* Xg = reinterpret_cast<const float4*>(X + (size_t)row0 * C_);
        #pragma unroll
        for (int k = 0; k < 8; ++k) {
            int f4 = tid + k * 256;
            int r = f4 >> 4, c4 = f4 & 15;
            float4 x = Xg[f4];
            u32x2 p;
            p[0] = pk2(x.x, x.y);
            p[1] = pk2(x.z, x.w);
            *reinterpret_cast<u32x2*>(&Xs[r * 36 + c4 * 2]) = p;
        }
    }
    __syncthreads();

    const int b  = row0 / S_;
    const int sb = row0 % S_;
    const unsigned short* Wtm = Wt + (size_t)(m * 128) * 64;
    const float* bm = bias + m * 128;
    unsigned short* Out = (m == 0) ? Qo : (m == 1) ? Ko : Vo;

    #pragma unroll
    for (int ni = 0; ni < 2; ++ni) {
        const int nt = 2 * w + ni;           // n-tile 0..7
        const int n0 = nt * 16;
        bf16x8 wf0 = *reinterpret_cast<const bf16x8*>(Wtm + (size_t)(n0 + lq) * 64 + lg * 8);
        bf16x8 wf1 = *reinterpret_cast<const bf16x8*>(Wtm + (size_t)(n0 + lq) * 64 + 32 + lg * 8);

        if (m != 2) {
            const int nrow = n0 + 4 * lg;                 // 4 consecutive n
            const int h = nrow >> 5, d0 = nrow & 31;
            f32x4 bv4 = *reinterpret_cast<const f32x4*>(bm + nrow);
            unsigned short* obase = Out + ((size_t)(b * H_ + h) * S_ + sb) * D_ + d0;
            #pragma unroll
            for (int st = 0; st < 8; ++st) {
                const unsigned int* xr = &Xs[(st * 16 + lq) * 36];
                bf16x8 xf0 = *reinterpret_cast<const bf16x8*>(xr + lg * 4);
                bf16x8 xf1 = *reinterpret_cast<const bf16x8*>(xr + 16 + lg * 4);
                f32x4 acc;
                acc[0] = 0.f; acc[1] = 0.f; acc[2] = 0.f; acc[3] = 0.f;
                acc = __builtin_amdgcn_mfma_f32_16x16x32_bf16(wf0, xf0, acc, 0, 0, 0);
                acc = __builtin_amdgcn_mfma_f32_16x16x32_bf16(wf1, xf1, acc, 0, 0, 0);
                u32x2 cc;
                cc[0] = pk2(acc[0] + bv4[0], acc[1] + bv4[1]);
                cc[1] = pk2(acc[2] + bv4[2], acc[3] + bv4[3]);
                *reinterpret_cast<u32x2*>(obase + (size_t)(st * 16 + lq) * D_) = cc;
            }
        } else {
            const int ncol = n0 + lq;                     // one n (= h,d) per lane
            const int h = ncol >> 5, d = ncol & 31;
            const float bsc = bm[ncol];
            unsigned short* obase = Out + ((size_t)(b * H_ + h) * S_) * D_
                                  + (size_t)d * S_ + sb + 4 * lg;
            #pragma unroll
            for (int st = 0; st < 8; ++st) {
                const unsigned int* xr = &Xs[(st * 16 + lq) * 36];
                bf16x8 xf0 = *reinterpret_cast<const bf16x8*>(xr + lg * 4);
                bf16x8 xf1 = *reinterpret_cast<const bf16x8*>(xr + 16 + lg * 4);
                f32x4 acc;
                acc[0] = 0.f; acc[1] = 0.f; acc[2] = 0.f; acc[3] = 0.f;
                acc = __builtin_amdgcn_mfma_f32_16x16x32_bf16(xf0, wf0, acc, 0, 0, 0);
                acc = __builtin_amdgcn_mfma_f32_16x16x32_bf16(xf1, wf1, acc, 0, 0, 0);
                u32x2 cc;
                cc[0] = pk2(acc[0] + bsc, acc[1] + bsc);
                cc[1] = pk2(acc[2] + bsc, acc[3] + bsc);
                *reinterpret_cast<u32x2*>(obase + st * 16) = cc;
            }
        }
    }
}

// ---------------- K2: MFMA attention + peeled register prefetch ------------
// grid 1024 (bh*2+half), 256 thr = 4 waves; wave owns 64 q rows (qi=4).
// One-tile-ahead prefetch, PEELED (no guards, no asm): prologue loads tile 0;
// body loads tile tc+1 unconditionally, computes tile tc from registers, then
// copies nxt->cur (the vmcnt wait lands AFTER the compute phase). Epilogue
// computes tile 15. vs R7: no inline-asm cvtpk, no conditional reg writes.
__global__ __launch_bounds__(256, 4) void attn_kernel(
    const unsigned short* __restrict__ Qb, const unsigned short* __restrict__ Kb,
    const unsigned short* __restrict__ Vtb, unsigned short* __restrict__ ctx)
{
    const int bid  = blockIdx.x;
    const int bh   = bid >> 1, half = bid & 1;
    const int b    = bh >> 2, h = bh & 3;
    const int tid  = threadIdx.x;
    const int w    = tid >> 6, lane = tid & 63;
    const int lq   = lane & 15, lg = lane >> 4;

    const unsigned short* Qp = Qb  + (size_t)bh * (S_ * D_);
    const unsigned short* Kp = Kb  + (size_t)bh * (S_ * D_);
    const unsigned short* Vp = Vtb + (size_t)bh * (S_ * D_);

    const int q0 = half * 256 + w * 64;

    bf16x8 qf[4];
    #pragma unroll
    for (int qi = 0; qi < 4; ++qi)
        qf[qi] = *reinterpret_cast<const bf16x8*>(
            Qp + (size_t)(q0 + qi * 16 + lq) * D_ + lg * 8);

    f32x4 acc[4][2];
    float lsum[4];
    #pragma unroll
    for (int qi = 0; qi < 4; ++qi) {
        lsum[qi] = 0.f;
        #pragma unroll
        for (int dt = 0; dt < 2; ++dt) {
            acc[qi][dt][0] = 0.f; acc[qi][dt][1] = 0.f;
            acc[qi][dt][2] = 0.f; acc[qi][dt][3] = 0.f;
        }
    }

    const unsigned short* kp0 = Kp + (size_t)lq * D_ + lg * 8;
    const unsigned short* kp1 = Kp + (size_t)(16 + lq) * D_ + lg * 8;
    const unsigned short* vp0 = Vp + (size_t)lq * S_ + 4 * lg;         // d=lq
    const unsigned short* vp1 = Vp + (size_t)(16 + lq) * S_ + 4 * lg;  // d=16+lq

    // compute one 32-t tile entirely from registers
    auto compute = [&](bf16x8 k0, bf16x8 k1, u32x2 va, u32x2 vb,
                       u32x2 vc, u32x2 vd) __attribute__((always_inline)) {
        u32x4 v0u, v1u;
        v0u[0] = va[0]; v0u[1] = va[1]; v0u[2] = vb[0]; v0u[3] = vb[1];
        v1u[0] = vc[0]; v1u[1] = vc[1]; v1u[2] = vd[0]; v1u[3] = vd[1];
        bf16x8 v0 = __builtin_bit_cast(bf16x8, v0u);
        bf16x8 v1 = __builtin_bit_cast(bf16x8, v1u);
        #pragma unroll
        for (int qi = 0; qi < 4; ++qi) {
            f32x4 z; z[0] = 0.f; z[1] = 0.f; z[2] = 0.f; z[3] = 0.f;
            f32x4 s0 = __builtin_amdgcn_mfma_f32_16x16x32_bf16(k0, qf[qi], z, 0, 0, 0);
            f32x4 s1 = __builtin_amdgcn_mfma_f32_16x16x32_bf16(k1, qf[qi], z, 0, 0, 0);
            float pa = __builtin_amdgcn_exp2f(s0[0]);
            float pb = __builtin_amdgcn_exp2f(s0[1]);
            float pc = __builtin_amdgcn_exp2f(s0[2]);
            float pd = __builtin_amdgcn_exp2f(s0[3]);
            float pe = __builtin_amdgcn_exp2f(s1[0]);
            float pf = __builtin_amdgcn_exp2f(s1[1]);
            float pg = __builtin_amdgcn_exp2f(s1[2]);
            float ph = __builtin_amdgcn_exp2f(s1[3]);
            lsum[qi] += ((pa + pb) + (pc + pd)) + ((pe + pf) + (pg + ph));
            u32x4 pu;
            pu[0] = pk2(pa, pb);
            pu[1] = pk2(pc, pd);
            pu[2] = pk2(pe, pf);
            pu[3] = pk2(pg, ph);
            bf16x8 pfr = __builtin_bit_cast(bf16x8, pu);
            acc[qi][0] = __builtin_amdgcn_mfma_f32_16x16x32_bf16(v0, pfr, acc[qi][0], 0, 0, 0);
            acc[qi][1] = __builtin_amdgcn_mfma_f32_16x16x32_bf16(v1, pfr, acc[qi][1], 0, 0, 0);
        }
    };

    // prologue: tile 0
    bf16x8 ck0 = *reinterpret_cast<const bf16x8*>(kp0);
    bf16x8 ck1 = *reinterpret_cast<const bf16x8*>(kp1);
    u32x2 cva = *reinterpret_cast<const u32x2*>(vp0);
    u32x2 cvb = *reinterpret_cast<const u32x2*>(vp0 + 16);
    u32x2 cvc = *reinterpret_cast<const u32x2*>(vp1);
    u32x2 cvd = *reinterpret_cast<const u32x2*>(vp1 + 16);

    for (int tc = 0; tc < 15; ++tc) {
        const int tn = (tc + 1) * 32;
        bf16x8 nk0 = *reinterpret_cast<const bf16x8*>(kp0 + (size_t)tn * D_);
        bf16x8 nk1 = *reinterpret_cast<const bf16x8*>(kp1 + (size_t)tn * D_);
        u32x2 nva = *reinterpret_cast<const u32x2*>(vp0 + tn);
        u32x2 nvb = *reinterpret_cast<const u32x2*>(vp0 + tn + 16);
        u32x2 nvc = *reinterpret_cast<const u32x2*>(vp1 + tn);
        u32x2 nvd = *reinterpret_cast<const u32x2*>(vp1 + tn + 16);

        compute(ck0, ck1, cva, cvb, cvc, cvd);

        ck0 = nk0; ck1 = nk1;
        cva = nva; cvb = nvb; cvc = nvc; cvd = nvd;
    }
    // epilogue: tile 15
    compute(ck0, ck1, cva, cvb, cvc, cvd);

    #pragma unroll
    for (int qi = 0; qi < 4; ++qi) {
        float lt = lsum[qi];
        lt += __shfl_xor(lt, 16, 64);
        lt += __shfl_xor(lt, 32, 64);
        const float inv = 1.0f / lt;
        const int qg = q0 + qi * 16 + lq;
        #pragma unroll
        for (int dt = 0; dt < 2; ++dt) {
            u32x2 c;
            c[0] = pk2(acc[qi][dt][0] * inv, acc[qi][dt][1] * inv);
            c[1] = pk2(acc[qi][dt][2] * inv, acc[qi][dt][3] * inv);
            unsigned short* cp = ctx + ((size_t)(b * S_ + qg)) * (H_ * D_)
                               + h * D_ + dt * 16 + lg * 4;
            *reinterpret_cast<u32x2*>(cp) = c;
        }
    }
}

// ---------------- K3: output projection (bf16 ctx -> fp32 out) ----------------
__global__ __launch_bounds__(256) void out_kernel(
    const unsigned short* __restrict__ ctx, const float* __restrict__ Wo,
    const float* __restrict__ bo, float* __restrict__ out)
{
    __shared__ float4 Wos[128][8];
    const int tid = threadIdx.x;
    #pragma unroll
    for (int k = 0; k < 4; ++k) {
        int f4 = tid + k * 256;
        reinterpret_cast<float4*>(&Wos[0][0])[f4] =
            reinterpret_cast<const float4*>(Wo)[f4];
    }
    __syncthreads();

    const int r  = blockIdx.x * 32 + (tid >> 3);
    const int cq = tid & 7;
    const u32x4* c4 = reinterpret_cast<const u32x4*>(ctx + (size_t)r * 128);
    float4 b4 = reinterpret_cast<const float4*>(bo)[cq];
    float ax = b4.x, ay = b4.y, az = b4.z, aw = b4.w;

    #pragma unroll 4
    for (int o8 = 0; o8 < 16; ++o8) {
        u32x4 u = c4[o8];
        #pragma unroll
        for (int q = 0; q < 4; ++q) {
            float xlo = __uint_as_float(u[q] << 16);
            float xhi = __uint_as_float(u[q] & 0xFFFF0000u);
            float4 wlo = Wos[o8 * 8 + q * 2][cq];
            float4 whi = Wos[o8 * 8 + q * 2 + 1][cq];
            ax += xlo * wlo.x + xhi * whi.x;
            ay += xlo * wlo.y + xhi * whi.y;
            az += xlo * wlo.z + xhi * whi.z;
            aw += xlo * wlo.w + xhi * whi.w;
        }
    }
    reinterpret_cast<float4*>(out + (size_t)r * 32)[cq] = make_float4(ax, ay, az, aw);
}

extern "C" void kernel_launch(void* const* d_in, const int* in_sizes, int n_in,
                              void* d_out, int out_size, void* d_ws, size_t ws_size,
                              hipStream_t stream) {
    const float* X  = (const float*)d_in[0];
    const float* Wq = (const float*)d_in[1];
    const float* bq = (const float*)d_in[2];
    const float* Wk = (const float*)d_in[3];
    const float* bk = (const float*)d_in[4];
    const float* Wv = (const float*)d_in[5];
    const float* bv = (const float*)d_in[6];
    const float* Wo = (const float*)d_in[7];
    const float* bo = (const float*)d_in[8];
    float* out = (float*)d_out;

    const size_t per = (size_t)B_ * H_ * S_ * D_;            // 8388608
    const size_t need = 4 * per * sizeof(unsigned short) + 24576 * 2 + 384 * 4;
    if (ws_size < need) return;

    unsigned short* Qb   = (unsigned short*)d_ws;
    unsigned short* Kb   = Qb + per;
    unsigned short* Vtb  = Kb + per;
    unsigned short* ctx  = Vtb + per;
    unsigned short* Wt   = ctx + per;
    float*          bias = (float*)(Wt + 24576);

    wprep_kernel<<<97, 256, 0, stream>>>(Wq, bq, Wk, bk, Wv, bv, Wt, bias);
    qkv_kernel<<<dim3(512, 3), 256, 0, stream>>>(X, Wt, bias, Qb, Kb, Vtb);
    attn_kernel<<<1024, 256, 0, stream>>>(Qb, Kb, Vtb, ctx);
    out_kernel<<<2048, 256, 0, stream>>>(ctx, Wo, bo, out);
}